// Round 9
// baseline (1496.493 us; speedup 1.0000x reference)
//
#include <hip/hip_runtime.h>
#include <hip/hip_bf16.h>

#define N_NODES 100000
#define N_HEDGES 100000
#define N_INC 1600000
#define D 128

#define B_KEYS 512            // keys per bucket
#define NBUCK 196             // ceil(100000/512)
#define CAP 10240             // bucket capacity (mean 8192, sigma ~90)
#define NBLKA ((N_INC + 1023) / 1024)   // 4 items/thread, 256 threads

#define LDA 136               // padded bf16 row stride for GEMM LDS tiles

typedef __attribute__((ext_vector_type(8))) short bf16x8;
typedef __attribute__((ext_vector_type(4))) float f32x4;

__device__ __forceinline__ short f2bf(float v) {
    __hip_bfloat16 b = __float2bfloat16(v);
    return *(short*)&b;
}
__device__ __forceinline__ unsigned packbf2(float x, float y) {
    __hip_bfloat162 p = __float22bfloat162_rn(make_float2(x, y));
    return *(unsigned*)&p;
}

// ---------------- W transpose + bf16 convert (once per call) ----------------
// also zeroes the gcnt counter block (block 0) so no memset dispatch is needed
__global__ void wt_kernel(const float* __restrict__ W1, const float* __restrict__ W2,
                          short* __restrict__ WT1, short* __restrict__ WT2,
                          int* __restrict__ gcnt) {
    if (blockIdx.x == 0) {
        for (int i = threadIdx.x; i < 2 * NBUCK; i += 256) gcnt[i] = 0;
    }
    int idx = blockIdx.x * 256 + threadIdx.x;     // 0..32767
    int sel = idx >> 14;
    int li = idx & 16383;
    int n = li >> 7, k = li & 127;
    const float* src = sel ? W2 : W1;
    short* dst = sel ? WT2 : WT1;
    dst[li] = f2bf(src[k * 128 + n]);
}

// ---------------- Phase A: direct global-atomic bucket reservation ----------------
// 3.2M device atomics over 784 counters (~4K/counter, parallel across L2 slices)
// replaces the two-phase LDS histogram: no barriers, one pass, packed stores.
__launch_bounds__(256)
__global__ void binA_kernel(const int* __restrict__ nidx, const int* __restrict__ hidx,
                            int* __restrict__ gcnt_e, int* __restrict__ gcnt_n,
                            unsigned* __restrict__ bin_e, unsigned* __restrict__ bin_n) {
    int base = (blockIdx.x * 256 + threadIdx.x) * 4;
    if (base + 4 <= N_INC) {
        int4 h4 = *(const int4*)(hidx + base);
        int4 n4 = *(const int4*)(nidx + base);
        int hs[4] = {h4.x, h4.y, h4.z, h4.w};
        int ns[4] = {n4.x, n4.y, n4.z, n4.w};
#pragma unroll
        for (int k = 0; k < 4; ++k) {
            int h = hs[k], n = ns[k];
            int be = h >> 9, bn = n >> 9;
            int oe = atomicAdd(&gcnt_e[be], 1);
            if (oe < CAP) bin_e[(size_t)be * CAP + oe] = ((unsigned)(h & 511) << 17) | (unsigned)n;
            int on = atomicAdd(&gcnt_n[bn], 1);
            if (on < CAP) bin_n[(size_t)bn * CAP + on] = ((unsigned)(n & 511) << 17) | (unsigned)h;
        }
    } else {
        for (int i = base; i < N_INC; ++i) {
            int h = hidx[i], n = nidx[i];
            int be = h >> 9, bn = n >> 9;
            int oe = atomicAdd(&gcnt_e[be], 1);
            if (oe < CAP) bin_e[(size_t)be * CAP + oe] = ((unsigned)(h & 511) << 17) | (unsigned)n;
            int on = atomicAdd(&gcnt_n[bn], 1);
            if (on < CAP) bin_n[(size_t)bn * CAP + on] = ((unsigned)(n & 511) << 17) | (unsigned)h;
        }
    }
}

// ---------------- Phase B: per-bucket counting sort, wave-shuffle scan ----------
__launch_bounds__(512)
__global__ void binB2_kernel(const int* __restrict__ gcnt_e, const unsigned* __restrict__ bin_e,
                             int* __restrict__ csr_e, int* __restrict__ segs_e,
                             int* __restrict__ segc_e, float* __restrict__ scale_e,
                             const int* __restrict__ gcnt_n, const unsigned* __restrict__ bin_n,
                             int* __restrict__ csr_n, int* __restrict__ segs_n,
                             int* __restrict__ segc_n, float* __restrict__ scale_n) {
    __shared__ int kc[B_KEYS];
    __shared__ int wsum[8];
    int b = blockIdx.x;
    const int* gcnt;  const unsigned* bin;  int* csr;  int* seg_start;  int* seg_cnt;  float* scale;
    if (b < NBUCK) { gcnt = gcnt_e; bin = bin_e; csr = csr_e; seg_start = segs_e; seg_cnt = segc_e; scale = scale_e; }
    else { b -= NBUCK; gcnt = gcnt_n; bin = bin_n; csr = csr_n; seg_start = segs_n; seg_cnt = segc_n; scale = scale_n; }
    int t = threadIdx.x;
    int lane = t & 63, wv = t >> 6;
    int cnt = gcnt[b];
    if (cnt > CAP) cnt = CAP;
    kc[t] = 0;
    __syncthreads();
    const unsigned* items = bin + (size_t)b * CAP;
    for (int i = t; i < cnt; i += 512) atomicAdd(&kc[items[i] >> 17], 1);
    __syncthreads();
    int mycnt = kc[t];
    // inclusive scan: per-wave shfl_up, then wave-sum combine
    int v = mycnt;
#pragma unroll
    for (int off = 1; off < 64; off <<= 1) {
        int u = __shfl_up(v, off);
        if (lane >= off) v += u;
    }
    if (lane == 63) wsum[wv] = v;
    __syncthreads();
    int addp = 0;
#pragma unroll
    for (int w = 0; w < 7; ++w) addp += (w < wv) ? wsum[w] : 0;
    int incl = v + addp;
    int sstart = b * CAP + (incl - mycnt);   // exclusive start
    int k = b * B_KEYS + t;
    if (k < N_NODES) {
        seg_start[k] = sstart;
        seg_cnt[k] = mycnt;
        scale[k] = mycnt ? 1.0f / (float)mycnt : 0.0f;
    }
    kc[t] = sstart;      // own slot only; all reads of kc happened before
    __syncthreads();
    for (int i = t; i < cnt; i += 512) {
        unsigned it = items[i];
        int pos = atomicAdd(&kc[it >> 17], 1);
        csr[pos] = (int)(it & 0x1FFFFu);
    }
}

// ---------------- MFMA bf16 GEMM: Y[nrows,128](bf16) = X[nrows,128] * W ----
// A-fragments loaded directly from global; only W^T in LDS (reused for epilogue).
template <typename T>
__launch_bounds__(256)
__global__ void gemm_mfma_kernel(const T* __restrict__ X, const short* __restrict__ WT,
                                 __hip_bfloat16* __restrict__ Y, int nrows) {
    __shared__ short lds_w[128 * LDA];   // W^T [n][k]; later reused for C staging
    int tid = threadIdx.x;
    int row0 = blockIdx.x * 64;

    // stage W^T bf16 -> LDS (uint4 copy, 2048 x 16 B)
    {
        const uint4* w4 = (const uint4*)WT;
#pragma unroll
        for (int i = 0; i < 8; ++i) {
            int idx = tid + i * 256;          // 0..2047 = 128 rows x 16 uint4
            int n = idx >> 4, g = idx & 15;
            *(uint4*)(lds_w + n * LDA + g * 8) = w4[idx];
        }
    }

    int wv = tid >> 6, lane = tid & 63;
    int m = lane & 15, quad = lane >> 4;
    int row = row0 + wv * 16 + m;
    bool rowok = row < nrows;

    // A fragments: A[row][quad*8 + k0*32 + j], straight from global
    bf16x8 af[4];
    if constexpr (sizeof(T) == 4) {
        const float* xr = (const float*)X + (size_t)row * 128 + quad * 8;
#pragma unroll
        for (int k0 = 0; k0 < 4; ++k0) {
            float4 a0 = make_float4(0.f, 0.f, 0.f, 0.f), a1 = a0;
            if (rowok) {
                a0 = *(const float4*)(xr + k0 * 32);
                a1 = *(const float4*)(xr + k0 * 32 + 4);
            }
            bf16x8 f;
            f[0] = f2bf(a0.x); f[1] = f2bf(a0.y); f[2] = f2bf(a0.z); f[3] = f2bf(a0.w);
            f[4] = f2bf(a1.x); f[5] = f2bf(a1.y); f[6] = f2bf(a1.z); f[7] = f2bf(a1.w);
            af[k0] = f;
        }
    } else {
        const short* xr = (const short*)X + (size_t)row * 128 + quad * 8;
#pragma unroll
        for (int k0 = 0; k0 < 4; ++k0) {
            bf16x8 f = {0, 0, 0, 0, 0, 0, 0, 0};
            if (rowok) f = *(const bf16x8*)(xr + k0 * 32);
            af[k0] = f;
        }
    }
    __syncthreads();   // W staged

    f32x4 zero = {0.f, 0.f, 0.f, 0.f};
    f32x4 acc[8];
#pragma unroll
    for (int t8 = 0; t8 < 8; ++t8) acc[t8] = zero;

#pragma unroll
    for (int t8 = 0; t8 < 8; ++t8) {
        const short* brow = lds_w + (t8 * 16 + m) * LDA + quad * 8;  // W^T[n][k], n = t8*16+m
#pragma unroll
        for (int k0 = 0; k0 < 4; ++k0) {
            bf16x8 bf = *(const bf16x8*)(brow + k0 * 32);
            acc[t8] = __builtin_amdgcn_mfma_f32_16x16x32_bf16(af[k0], bf, acc[t8], 0, 0, 0);
        }
    }

    __syncthreads();   // all W ds_reads done; safe to reuse lds_w for C
    // C/D layout: col = lane&15, row = quad*4 + reg
#pragma unroll
    for (int t8 = 0; t8 < 8; ++t8) {
#pragma unroll
        for (int r = 0; r < 4; ++r) {
            int crow = wv * 16 + quad * 4 + r;
            int col = t8 * 16 + m;
            lds_w[crow * LDA + col] = f2bf(acc[t8][r]);
        }
    }
    __syncthreads();
    // coalesced store: 64 rows x 16 uint4
#pragma unroll
    for (int i = 0; i < 4; ++i) {
        int f4 = tid + i * 256;               // 0..1023
        int r = f4 >> 4, g = f4 & 15;
        if (row0 + r < nrows) {
            uint4 u = *(const uint4*)(lds_w + r * LDA + g * 8);
            *(uint4*)((char*)Y + (size_t)(row0 + r) * 256 + g * 16) = u;
        }
    }
}

// ---------------- segment gather-sum: 4 rows per vmem instruction ----------------
// (round-5 proven version: at the 8x-XCD L2-fill floor, ~60 us/pass)
__device__ __forceinline__ void acc8_add(float* a, uint4 u) {
    a[0] += __uint_as_float(u.x << 16); a[1] += __uint_as_float(u.x & 0xFFFF0000u);
    a[2] += __uint_as_float(u.y << 16); a[3] += __uint_as_float(u.y & 0xFFFF0000u);
    a[4] += __uint_as_float(u.z << 16); a[5] += __uint_as_float(u.z & 0xFFFF0000u);
    a[6] += __uint_as_float(u.w << 16); a[7] += __uint_as_float(u.w & 0xFFFF0000u);
}
__device__ __forceinline__ void acc8_fma(float* a, uint4 u, float msk) {
    a[0] = fmaf(msk, __uint_as_float(u.x << 16), a[0]);
    a[1] = fmaf(msk, __uint_as_float(u.x & 0xFFFF0000u), a[1]);
    a[2] = fmaf(msk, __uint_as_float(u.y << 16), a[2]);
    a[3] = fmaf(msk, __uint_as_float(u.y & 0xFFFF0000u), a[3]);
    a[4] = fmaf(msk, __uint_as_float(u.z << 16), a[4]);
    a[5] = fmaf(msk, __uint_as_float(u.z & 0xFFFF0000u), a[5]);
    a[6] = fmaf(msk, __uint_as_float(u.w << 16), a[6]);
    a[7] = fmaf(msk, __uint_as_float(u.w & 0xFFFF0000u), a[7]);
}

__device__ __forceinline__ void seg_sum_rows(const char* __restrict__ src,
                                             const int* __restrict__ col,
                                             int s, int e, int lane, float* acc) {
    int fl = lane & 15, sub = lane >> 4;
    for (int base = s; base < e; base += 64) {
        int j = base + lane;
        int myidx = (j < e) ? col[j] : 0;
        int cnt = e - base; if (cnt > 64) cnt = 64;
        int cnt4 = cnt & ~3;
        int m = 0;
        for (; m + 8 <= cnt4; m += 8) {           // 2 loads in flight
            int ia = __shfl(myidx, m + sub);
            int ib = __shfl(myidx, m + 4 + sub);
            uint4 ua = *(const uint4*)(src + (size_t)ia * 256 + fl * 16);
            uint4 ub = *(const uint4*)(src + (size_t)ib * 256 + fl * 16);
            acc8_add(acc, ua);
            acc8_add(acc, ub);
        }
        for (; m < cnt4; m += 4) {
            int ia = __shfl(myidx, m + sub);
            uint4 ua = *(const uint4*)(src + (size_t)ia * 256 + fl * 16);
            acc8_add(acc, ua);
        }
        if (m < cnt) {                            // masked tail batch
            int sl = m + sub;
            int slc = sl < cnt ? sl : cnt - 1;
            float msk = sl < cnt ? 1.0f : 0.0f;
            int ia = __shfl(myidx, slc);
            uint4 ua = *(const uint4*)(src + (size_t)ia * 256 + fl * 16);
            acc8_fma(acc, ua, msk);
        }
    }
}

__device__ __forceinline__ void cross_reduce8(float* a) {
#pragma unroll
    for (int i = 0; i < 8; ++i) {
        a[i] += __shfl_xor(a[i], 16);
        a[i] += __shfl_xor(a[i], 32);
    }
}

// e[h] = Binv[h] * sum_{nodes in h} src[node]     (bf16 out)
__launch_bounds__(256)
__global__ void edge_agg_kernel(const char* __restrict__ src,
                                const int* __restrict__ seg_start, const int* __restrict__ seg_cnt,
                                const int* __restrict__ col, const float* __restrict__ scale,
                                char* __restrict__ dst) {
    int wid = threadIdx.x >> 6, lane = threadIdx.x & 63;
    int seg = blockIdx.x * 4 + wid;
    int s = seg_start[seg], e = s + seg_cnt[seg];
    float acc[8] = {0.f, 0.f, 0.f, 0.f, 0.f, 0.f, 0.f, 0.f};
    seg_sum_rows(src, col, s, e, lane, acc);
    cross_reduce8(acc);
    if ((lane >> 4) == 0) {
        int fl = lane & 15;
        float sc = scale[seg];
        uint4 o;
        o.x = packbf2(acc[0] * sc, acc[1] * sc);
        o.y = packbf2(acc[2] * sc, acc[3] * sc);
        o.z = packbf2(acc[4] * sc, acc[5] * sc);
        o.w = packbf2(acc[6] * sc, acc[7] * sc);
        *(uint4*)(dst + (size_t)seg * 256 + fl * 16) = o;
    }
}

// out[n] = relu(Dinv[n] * sum + bias)   (bf16 out)
__launch_bounds__(256)
__global__ void node_agg_relu_kernel(const char* __restrict__ src,
                                     const int* __restrict__ seg_start, const int* __restrict__ seg_cnt,
                                     const int* __restrict__ col, const float* __restrict__ scale,
                                     const float* __restrict__ bias,
                                     char* __restrict__ dst) {
    int wid = threadIdx.x >> 6, lane = threadIdx.x & 63;
    int seg = blockIdx.x * 4 + wid;
    int s = seg_start[seg], e = s + seg_cnt[seg];
    float acc[8] = {0.f, 0.f, 0.f, 0.f, 0.f, 0.f, 0.f, 0.f};
    seg_sum_rows(src, col, s, e, lane, acc);
    cross_reduce8(acc);
    if ((lane >> 4) == 0) {
        int fl = lane & 15;
        float sc = scale[seg];
        const float4* b4 = (const float4*)(bias + fl * 8);
        float4 blo = b4[0], bhi = b4[1];
        uint4 o;
        o.x = packbf2(fmaxf(acc[0] * sc + blo.x, 0.f), fmaxf(acc[1] * sc + blo.y, 0.f));
        o.y = packbf2(fmaxf(acc[2] * sc + blo.z, 0.f), fmaxf(acc[3] * sc + blo.w, 0.f));
        o.z = packbf2(fmaxf(acc[4] * sc + bhi.x, 0.f), fmaxf(acc[5] * sc + bhi.y, 0.f));
        o.w = packbf2(fmaxf(acc[6] * sc + bhi.z, 0.f), fmaxf(acc[7] * sc + bhi.w, 0.f));
        *(uint4*)(dst + (size_t)seg * 256 + fl * 16) = o;
    }
}

// final layer: relu node output -> per-block partial column sums (f32)
__launch_bounds__(256)
__global__ void node_agg_final_kernel(const char* __restrict__ src,
                                      const int* __restrict__ seg_start, const int* __restrict__ seg_cnt,
                                      const int* __restrict__ col, const float* __restrict__ scale,
                                      const float* __restrict__ bias,
                                      float* __restrict__ partials) {
    __shared__ __align__(16) float sd[4 * 128];
    int wid = threadIdx.x >> 6, lane = threadIdx.x & 63;
    int seg = blockIdx.x * 4 + wid;
    int s = seg_start[seg], e = s + seg_cnt[seg];
    float acc[8] = {0.f, 0.f, 0.f, 0.f, 0.f, 0.f, 0.f, 0.f};
    seg_sum_rows(src, col, s, e, lane, acc);
    cross_reduce8(acc);
    if ((lane >> 4) == 0) {
        int fl = lane & 15;
        float sc = scale[seg];
        const float4* b4 = (const float4*)(bias + fl * 8);
        float4 blo = b4[0], bhi = b4[1];
        float4* d = (float4*)(sd + wid * 128 + fl * 8);
        d[0] = make_float4(fmaxf(acc[0] * sc + blo.x, 0.f), fmaxf(acc[1] * sc + blo.y, 0.f),
                           fmaxf(acc[2] * sc + blo.z, 0.f), fmaxf(acc[3] * sc + blo.w, 0.f));
        d[1] = make_float4(fmaxf(acc[4] * sc + bhi.x, 0.f), fmaxf(acc[5] * sc + bhi.y, 0.f),
                           fmaxf(acc[6] * sc + bhi.z, 0.f), fmaxf(acc[7] * sc + bhi.w, 0.f));
    }
    __syncthreads();
    int t = threadIdx.x;
    if (t < 128) {
        partials[(size_t)blockIdx.x * 128 + t] =
            sd[t] + sd[128 + t] + sd[256 + t] + sd[384 + t];
    }
}

// ---------------- mean reduction, coalesced two-stage ----------------
__launch_bounds__(256)
__global__ void mean_stage1_kernel(const float* __restrict__ partials, float* __restrict__ partials2,
                                   int nrows) {
    __shared__ __align__(16) float4 s4[256];
    int t = threadIdx.x;
    int c4 = t & 31, r8 = t >> 5;
    float4 a = make_float4(0.f, 0.f, 0.f, 0.f);
    for (int r = blockIdx.x * 8 + r8; r < nrows; r += 256 * 8) {
        float4 v = ((const float4*)partials)[(size_t)r * 32 + c4];
        a.x += v.x; a.y += v.y; a.z += v.z; a.w += v.w;
    }
    s4[t] = a;
    __syncthreads();
    if (t < 32) {
        float4 v = s4[t];
#pragma unroll
        for (int i = 1; i < 8; ++i) {
            float4 u = s4[t + 32 * i];
            v.x += u.x; v.y += u.y; v.z += u.z; v.w += u.w;
        }
        ((float4*)partials2)[(size_t)blockIdx.x * 32 + t] = v;
    }
}

__launch_bounds__(256)
__global__ void mean_stage2_kernel(const float* __restrict__ partials2, float* __restrict__ out) {
    __shared__ __align__(16) float4 s4[256];
    int t = threadIdx.x;
    int c4 = t & 31, r8 = t >> 5;
    float4 a = make_float4(0.f, 0.f, 0.f, 0.f);
    for (int r = r8; r < 256; r += 8) {
        float4 v = ((const float4*)partials2)[(size_t)r * 32 + c4];
        a.x += v.x; a.y += v.y; a.z += v.z; a.w += v.w;
    }
    s4[t] = a;
    __syncthreads();
    if (t < 32) {
        float4 v = s4[t];
#pragma unroll
        for (int i = 1; i < 8; ++i) {
            float4 u = s4[t + 32 * i];
            v.x += u.x; v.y += u.y; v.z += u.z; v.w += u.w;
        }
        const float inv = 1.0f / (float)N_NODES;
        v.x *= inv; v.y *= inv; v.z *= inv; v.w *= inv;
        ((float4*)out)[t] = v;
    }
}

// ---------------- launch ----------------
extern "C" void kernel_launch(void* const* d_in, const int* in_sizes, int n_in,
                              void* d_out, int out_size, void* d_ws, size_t ws_size,
                              hipStream_t stream) {
    const float* x  = (const float*)d_in[0];
    const int*   ei = (const int*)d_in[1];
    const float* w1 = (const float*)d_in[2];
    const float* b1 = (const float*)d_in[3];
    const float* w2 = (const float*)d_in[4];
    const float* b2 = (const float*)d_in[5];
    float* out = (float*)d_out;
    const int* nidx = ei;
    const int* hidx = ei + N_INC;

    char* wsp = (char*)d_ws;
    size_t off = 0;
    auto alloc = [&](size_t bytes) -> void* {
        void* p = wsp + off;
        off += (bytes + 255) & ~(size_t)255;
        return p;
    };

    char* B0         = (char*)alloc((size_t)N_NODES * 128 * 2);
    char* B1         = (char*)alloc((size_t)N_NODES * 128 * 2);
    unsigned* bin_e  = (unsigned*)alloc((size_t)NBUCK * CAP * 4);
    unsigned* bin_n  = (unsigned*)alloc((size_t)NBUCK * CAP * 4);
    int* csr_e       = (int*)alloc((size_t)NBUCK * CAP * 4);
    int* csr_n       = (int*)alloc((size_t)NBUCK * CAP * 4);
    float* partials  = (float*)alloc((size_t)(N_NODES / 4) * 128 * 4);
    float* partials2 = (float*)alloc((size_t)256 * 128 * 4);
    int* segs_e      = (int*)alloc((size_t)N_NODES * 4);
    int* segc_e      = (int*)alloc((size_t)N_NODES * 4);
    int* segs_n      = (int*)alloc((size_t)N_NODES * 4);
    int* segc_n      = (int*)alloc((size_t)N_NODES * 4);
    float* scale_e   = (float*)alloc((size_t)N_NODES * 4);
    float* scale_n   = (float*)alloc((size_t)N_NODES * 4);
    short* WT1       = (short*)alloc((size_t)128 * 128 * 2);
    short* WT2       = (short*)alloc((size_t)128 * 128 * 2);
    // contiguous counter block, zeroed by wt_kernel block 0 (no memset dispatch)
    int* gcnt        = (int*)alloc((size_t)2 * NBUCK * 4);
    int* gcnt_e = gcnt;
    int* gcnt_n = gcnt + NBUCK;

    wt_kernel<<<128, 256, 0, stream>>>(w1, w2, WT1, WT2, gcnt);
    binA_kernel<<<NBLKA, 256, 0, stream>>>(nidx, hidx, gcnt_e, gcnt_n, bin_e, bin_n);
    binB2_kernel<<<2 * NBUCK, 512, 0, stream>>>(gcnt_e, bin_e, csr_e, segs_e, segc_e, scale_e,
                                                gcnt_n, bin_n, csr_n, segs_n, segc_n, scale_n);

    int gGemm = (N_NODES + 63) / 64;
    int gSeg = N_NODES / 4;

    // layer 1
    gemm_mfma_kernel<float><<<gGemm, 256, 0, stream>>>(x, WT1, (__hip_bfloat16*)B0, N_NODES);
    edge_agg_kernel<<<gSeg, 256, 0, stream>>>(B0, segs_e, segc_e, csr_e, scale_e, B1);
    node_agg_relu_kernel<<<gSeg, 256, 0, stream>>>(B1, segs_n, segc_n, csr_n, scale_n, b1, B0);
    // layer 2
    gemm_mfma_kernel<__hip_bfloat16><<<gGemm, 256, 0, stream>>>((const __hip_bfloat16*)B0, WT2,
                                                                (__hip_bfloat16*)B1, N_NODES);
    edge_agg_kernel<<<gSeg, 256, 0, stream>>>(B1, segs_e, segc_e, csr_e, scale_e, B0);
    node_agg_final_kernel<<<gSeg, 256, 0, stream>>>(B0, segs_n, segc_n, csr_n, scale_n, b2, partials);
    mean_stage1_kernel<<<256, 256, 0, stream>>>(partials, partials2, N_NODES / 4);
    mean_stage2_kernel<<<1, 256, 0, stream>>>(partials2, out);
}

// Round 10
// 417.599 us; speedup vs baseline: 3.5836x; 3.5836x over previous
//
#include <hip/hip_runtime.h>
#include <hip/hip_bf16.h>

#define N_NODES 100000
#define N_HEDGES 100000
#define N_INC 1600000
#define D 128

#define B_KEYS 512            // keys per bucket
#define NBUCK 196             // ceil(100000/512)
#define CAP 10240             // bucket capacity (mean 8192, sigma ~90)
#define CHUNK 4096            // 16 items per thread, register-resident
#define NBLKA ((N_INC + CHUNK - 1) / CHUNK)   // 391

#define LDA 136               // padded bf16 row stride for GEMM LDS tiles

typedef __attribute__((ext_vector_type(8))) short bf16x8;
typedef __attribute__((ext_vector_type(4))) float f32x4;

__device__ __forceinline__ short f2bf(float v) {
    __hip_bfloat16 b = __float2bfloat16(v);
    return *(short*)&b;
}
__device__ __forceinline__ unsigned packbf2(float x, float y) {
    __hip_bfloat162 p = __float22bfloat162_rn(make_float2(x, y));
    return *(unsigned*)&p;
}

// ---------------- W transpose + bf16 convert (once per call) ----------------
// also zeroes the gcnt counter block (block 0) so no memset dispatch is needed
__global__ void wt_kernel(const float* __restrict__ W1, const float* __restrict__ W2,
                          short* __restrict__ WT1, short* __restrict__ WT2,
                          int* __restrict__ gcnt) {
    if (blockIdx.x == 0) {
        for (int i = threadIdx.x; i < 2 * NBUCK; i += 256) gcnt[i] = 0;
    }
    int idx = blockIdx.x * 256 + threadIdx.x;     // 0..32767
    int sel = idx >> 14;
    int li = idx & 16383;
    int n = li >> 7, k = li & 127;
    const float* src = sel ? W2 : W1;
    short* dst = sel ? WT2 : WT1;
    dst[li] = f2bf(src[k * 128 + n]);
}

// ---------------- Phase A: bucket partition, register-resident chunk ----------------
// two-phase LDS histogram: ONE global atomic per (block,bucket) for range
// reservation. Round-9 lesson: direct per-item global atomics on 784 shared
// counters serialize at ~650 cyc each (cross-XCD coherence latency) -> 1.1 ms.
__launch_bounds__(256)
__global__ void binA_kernel(const int* __restrict__ nidx, const int* __restrict__ hidx,
                            int* __restrict__ gcnt_e, int* __restrict__ gcnt_n,
                            unsigned* __restrict__ bin_e, unsigned* __restrict__ bin_n) {
    __shared__ int hist_e[NBUCK], hist_n[NBUCK], base_e[NBUCK], base_n[NBUCK];
    int t = threadIdx.x;
    int items_h[16], items_n[16];
    int start = blockIdx.x * CHUNK;
#pragma unroll
    for (int k = 0; k < 16; ++k) {
        int i = start + t + k * 256;
        bool ok = i < N_INC;
        items_h[k] = ok ? hidx[i] : -1;
        items_n[k] = ok ? nidx[i] : -1;
    }
    for (int b = t; b < NBUCK; b += 256) { hist_e[b] = 0; hist_n[b] = 0; }
    __syncthreads();
#pragma unroll
    for (int k = 0; k < 16; ++k) {
        if (items_h[k] >= 0) {
            atomicAdd(&hist_e[items_h[k] >> 9], 1);
            atomicAdd(&hist_n[items_n[k] >> 9], 1);
        }
    }
    __syncthreads();
    for (int b = t; b < NBUCK; b += 256) {
        base_e[b] = atomicAdd(&gcnt_e[b], hist_e[b]);
        base_n[b] = atomicAdd(&gcnt_n[b], hist_n[b]);
        hist_e[b] = 0; hist_n[b] = 0;
    }
    __syncthreads();
#pragma unroll
    for (int k = 0; k < 16; ++k) {
        if (items_h[k] >= 0) {
            int h = items_h[k], n = items_n[k];
            int be = h >> 9, bn = n >> 9;
            int oe = base_e[be] + atomicAdd(&hist_e[be], 1);
            if (oe >= 0 && oe < CAP) bin_e[(size_t)be * CAP + oe] = ((unsigned)(h & 511) << 17) | (unsigned)n;
            int on = base_n[bn] + atomicAdd(&hist_n[bn], 1);
            if (on >= 0 && on < CAP) bin_n[(size_t)bn * CAP + on] = ((unsigned)(n & 511) << 17) | (unsigned)h;
        }
    }
}

// ---------------- Phase B: per-bucket counting sort, wave-shuffle scan ----------
__launch_bounds__(512)
__global__ void binB2_kernel(const int* __restrict__ gcnt_e, const unsigned* __restrict__ bin_e,
                             int* __restrict__ csr_e, int* __restrict__ segs_e,
                             int* __restrict__ segc_e, float* __restrict__ scale_e,
                             const int* __restrict__ gcnt_n, const unsigned* __restrict__ bin_n,
                             int* __restrict__ csr_n, int* __restrict__ segs_n,
                             int* __restrict__ segc_n, float* __restrict__ scale_n) {
    __shared__ int kc[B_KEYS];
    __shared__ int wsum[8];
    int b = blockIdx.x;
    const int* gcnt;  const unsigned* bin;  int* csr;  int* seg_start;  int* seg_cnt;  float* scale;
    if (b < NBUCK) { gcnt = gcnt_e; bin = bin_e; csr = csr_e; seg_start = segs_e; seg_cnt = segc_e; scale = scale_e; }
    else { b -= NBUCK; gcnt = gcnt_n; bin = bin_n; csr = csr_n; seg_start = segs_n; seg_cnt = segc_n; scale = scale_n; }
    int t = threadIdx.x;
    int lane = t & 63, wv = t >> 6;
    int cnt = gcnt[b];
    if (cnt > CAP) cnt = CAP;
    kc[t] = 0;
    __syncthreads();
    const unsigned* items = bin + (size_t)b * CAP;
    for (int i = t; i < cnt; i += 512) atomicAdd(&kc[items[i] >> 17], 1);
    __syncthreads();
    int mycnt = kc[t];
    // inclusive scan: per-wave shfl_up, then wave-sum combine
    int v = mycnt;
#pragma unroll
    for (int off = 1; off < 64; off <<= 1) {
        int u = __shfl_up(v, off);
        if (lane >= off) v += u;
    }
    if (lane == 63) wsum[wv] = v;
    __syncthreads();
    int addp = 0;
#pragma unroll
    for (int w = 0; w < 7; ++w) addp += (w < wv) ? wsum[w] : 0;
    int incl = v + addp;
    int sstart = b * CAP + (incl - mycnt);   // exclusive start
    int k = b * B_KEYS + t;
    if (k < N_NODES) {
        seg_start[k] = sstart;
        seg_cnt[k] = mycnt;
        scale[k] = mycnt ? 1.0f / (float)mycnt : 0.0f;
    }
    kc[t] = sstart;      // own slot only; all reads of kc happened before
    __syncthreads();
    for (int i = t; i < cnt; i += 512) {
        unsigned it = items[i];
        int pos = atomicAdd(&kc[it >> 17], 1);
        csr[pos] = (int)(it & 0x1FFFFu);
    }
}

// ---------------- MFMA bf16 GEMM: Y[nrows,128](bf16) = X[nrows,128] * W ----
// A-fragments loaded directly from global; only W^T in LDS (reused for epilogue).
template <typename T>
__launch_bounds__(256)
__global__ void gemm_mfma_kernel(const T* __restrict__ X, const short* __restrict__ WT,
                                 __hip_bfloat16* __restrict__ Y, int nrows) {
    __shared__ short lds_w[128 * LDA];   // W^T [n][k]; later reused for C staging
    int tid = threadIdx.x;
    int row0 = blockIdx.x * 64;

    // stage W^T bf16 -> LDS (uint4 copy, 2048 x 16 B)
    {
        const uint4* w4 = (const uint4*)WT;
#pragma unroll
        for (int i = 0; i < 8; ++i) {
            int idx = tid + i * 256;          // 0..2047 = 128 rows x 16 uint4
            int n = idx >> 4, g = idx & 15;
            *(uint4*)(lds_w + n * LDA + g * 8) = w4[idx];
        }
    }

    int wv = tid >> 6, lane = tid & 63;
    int m = lane & 15, quad = lane >> 4;
    int row = row0 + wv * 16 + m;
    bool rowok = row < nrows;

    // A fragments: A[row][quad*8 + k0*32 + j], straight from global
    bf16x8 af[4];
    if constexpr (sizeof(T) == 4) {
        const float* xr = (const float*)X + (size_t)row * 128 + quad * 8;
#pragma unroll
        for (int k0 = 0; k0 < 4; ++k0) {
            float4 a0 = make_float4(0.f, 0.f, 0.f, 0.f), a1 = a0;
            if (rowok) {
                a0 = *(const float4*)(xr + k0 * 32);
                a1 = *(const float4*)(xr + k0 * 32 + 4);
            }
            bf16x8 f;
            f[0] = f2bf(a0.x); f[1] = f2bf(a0.y); f[2] = f2bf(a0.z); f[3] = f2bf(a0.w);
            f[4] = f2bf(a1.x); f[5] = f2bf(a1.y); f[6] = f2bf(a1.z); f[7] = f2bf(a1.w);
            af[k0] = f;
        }
    } else {
        const short* xr = (const short*)X + (size_t)row * 128 + quad * 8;
#pragma unroll
        for (int k0 = 0; k0 < 4; ++k0) {
            bf16x8 f = {0, 0, 0, 0, 0, 0, 0, 0};
            if (rowok) f = *(const bf16x8*)(xr + k0 * 32);
            af[k0] = f;
        }
    }
    __syncthreads();   // W staged

    f32x4 zero = {0.f, 0.f, 0.f, 0.f};
    f32x4 acc[8];
#pragma unroll
    for (int t8 = 0; t8 < 8; ++t8) acc[t8] = zero;

#pragma unroll
    for (int t8 = 0; t8 < 8; ++t8) {
        const short* brow = lds_w + (t8 * 16 + m) * LDA + quad * 8;  // W^T[n][k], n = t8*16+m
#pragma unroll
        for (int k0 = 0; k0 < 4; ++k0) {
            bf16x8 bf = *(const bf16x8*)(brow + k0 * 32);
            acc[t8] = __builtin_amdgcn_mfma_f32_16x16x32_bf16(af[k0], bf, acc[t8], 0, 0, 0);
        }
    }

    __syncthreads();   // all W ds_reads done; safe to reuse lds_w for C
    // C/D layout: col = lane&15, row = quad*4 + reg
#pragma unroll
    for (int t8 = 0; t8 < 8; ++t8) {
#pragma unroll
        for (int r = 0; r < 4; ++r) {
            int crow = wv * 16 + quad * 4 + r;
            int col = t8 * 16 + m;
            lds_w[crow * LDA + col] = f2bf(acc[t8][r]);
        }
    }
    __syncthreads();
    // coalesced store: 64 rows x 16 uint4
#pragma unroll
    for (int i = 0; i < 4; ++i) {
        int f4 = tid + i * 256;               // 0..1023
        int r = f4 >> 4, g = f4 & 15;
        if (row0 + r < nrows) {
            uint4 u = *(const uint4*)(lds_w + r * LDA + g * 8);
            *(uint4*)((char*)Y + (size_t)(row0 + r) * 256 + g * 16) = u;
        }
    }
}

// ---------------- segment gather-sum: 4 rows per vmem instruction ----------------
// (round-5 proven version: at the 8x-XCD L2-fill floor, ~60 us/pass)
__device__ __forceinline__ void acc8_add(float* a, uint4 u) {
    a[0] += __uint_as_float(u.x << 16); a[1] += __uint_as_float(u.x & 0xFFFF0000u);
    a[2] += __uint_as_float(u.y << 16); a[3] += __uint_as_float(u.y & 0xFFFF0000u);
    a[4] += __uint_as_float(u.z << 16); a[5] += __uint_as_float(u.z & 0xFFFF0000u);
    a[6] += __uint_as_float(u.w << 16); a[7] += __uint_as_float(u.w & 0xFFFF0000u);
}
__device__ __forceinline__ void acc8_fma(float* a, uint4 u, float msk) {
    a[0] = fmaf(msk, __uint_as_float(u.x << 16), a[0]);
    a[1] = fmaf(msk, __uint_as_float(u.x & 0xFFFF0000u), a[1]);
    a[2] = fmaf(msk, __uint_as_float(u.y << 16), a[2]);
    a[3] = fmaf(msk, __uint_as_float(u.y & 0xFFFF0000u), a[3]);
    a[4] = fmaf(msk, __uint_as_float(u.z << 16), a[4]);
    a[5] = fmaf(msk, __uint_as_float(u.z & 0xFFFF0000u), a[5]);
    a[6] = fmaf(msk, __uint_as_float(u.w << 16), a[6]);
    a[7] = fmaf(msk, __uint_as_float(u.w & 0xFFFF0000u), a[7]);
}

__device__ __forceinline__ void seg_sum_rows(const char* __restrict__ src,
                                             const int* __restrict__ col,
                                             int s, int e, int lane, float* acc) {
    int fl = lane & 15, sub = lane >> 4;
    for (int base = s; base < e; base += 64) {
        int j = base + lane;
        int myidx = (j < e) ? col[j] : 0;
        int cnt = e - base; if (cnt > 64) cnt = 64;
        int cnt4 = cnt & ~3;
        int m = 0;
        for (; m + 8 <= cnt4; m += 8) {           // 2 loads in flight
            int ia = __shfl(myidx, m + sub);
            int ib = __shfl(myidx, m + 4 + sub);
            uint4 ua = *(const uint4*)(src + (size_t)ia * 256 + fl * 16);
            uint4 ub = *(const uint4*)(src + (size_t)ib * 256 + fl * 16);
            acc8_add(acc, ua);
            acc8_add(acc, ub);
        }
        for (; m < cnt4; m += 4) {
            int ia = __shfl(myidx, m + sub);
            uint4 ua = *(const uint4*)(src + (size_t)ia * 256 + fl * 16);
            acc8_add(acc, ua);
        }
        if (m < cnt) {                            // masked tail batch
            int sl = m + sub;
            int slc = sl < cnt ? sl : cnt - 1;
            float msk = sl < cnt ? 1.0f : 0.0f;
            int ia = __shfl(myidx, slc);
            uint4 ua = *(const uint4*)(src + (size_t)ia * 256 + fl * 16);
            acc8_fma(acc, ua, msk);
        }
    }
}

__device__ __forceinline__ void cross_reduce8(float* a) {
#pragma unroll
    for (int i = 0; i < 8; ++i) {
        a[i] += __shfl_xor(a[i], 16);
        a[i] += __shfl_xor(a[i], 32);
    }
}

// e[h] = Binv[h] * sum_{nodes in h} src[node]     (bf16 out)
__launch_bounds__(256)
__global__ void edge_agg_kernel(const char* __restrict__ src,
                                const int* __restrict__ seg_start, const int* __restrict__ seg_cnt,
                                const int* __restrict__ col, const float* __restrict__ scale,
                                char* __restrict__ dst) {
    int wid = threadIdx.x >> 6, lane = threadIdx.x & 63;
    int seg = blockIdx.x * 4 + wid;
    int s = seg_start[seg], e = s + seg_cnt[seg];
    float acc[8] = {0.f, 0.f, 0.f, 0.f, 0.f, 0.f, 0.f, 0.f};
    seg_sum_rows(src, col, s, e, lane, acc);
    cross_reduce8(acc);
    if ((lane >> 4) == 0) {
        int fl = lane & 15;
        float sc = scale[seg];
        uint4 o;
        o.x = packbf2(acc[0] * sc, acc[1] * sc);
        o.y = packbf2(acc[2] * sc, acc[3] * sc);
        o.z = packbf2(acc[4] * sc, acc[5] * sc);
        o.w = packbf2(acc[6] * sc, acc[7] * sc);
        *(uint4*)(dst + (size_t)seg * 256 + fl * 16) = o;
    }
}

// out[n] = relu(Dinv[n] * sum + bias)   (bf16 out)
__launch_bounds__(256)
__global__ void node_agg_relu_kernel(const char* __restrict__ src,
                                     const int* __restrict__ seg_start, const int* __restrict__ seg_cnt,
                                     const int* __restrict__ col, const float* __restrict__ scale,
                                     const float* __restrict__ bias,
                                     char* __restrict__ dst) {
    int wid = threadIdx.x >> 6, lane = threadIdx.x & 63;
    int seg = blockIdx.x * 4 + wid;
    int s = seg_start[seg], e = s + seg_cnt[seg];
    float acc[8] = {0.f, 0.f, 0.f, 0.f, 0.f, 0.f, 0.f, 0.f};
    seg_sum_rows(src, col, s, e, lane, acc);
    cross_reduce8(acc);
    if ((lane >> 4) == 0) {
        int fl = lane & 15;
        float sc = scale[seg];
        const float4* b4 = (const float4*)(bias + fl * 8);
        float4 blo = b4[0], bhi = b4[1];
        uint4 o;
        o.x = packbf2(fmaxf(acc[0] * sc + blo.x, 0.f), fmaxf(acc[1] * sc + blo.y, 0.f));
        o.y = packbf2(fmaxf(acc[2] * sc + blo.z, 0.f), fmaxf(acc[3] * sc + blo.w, 0.f));
        o.z = packbf2(fmaxf(acc[4] * sc + bhi.x, 0.f), fmaxf(acc[5] * sc + bhi.y, 0.f));
        o.w = packbf2(fmaxf(acc[6] * sc + bhi.z, 0.f), fmaxf(acc[7] * sc + bhi.w, 0.f));
        *(uint4*)(dst + (size_t)seg * 256 + fl * 16) = o;
    }
}

// final layer: relu node output -> per-block partial column sums (f32)
__launch_bounds__(256)
__global__ void node_agg_final_kernel(const char* __restrict__ src,
                                      const int* __restrict__ seg_start, const int* __restrict__ seg_cnt,
                                      const int* __restrict__ col, const float* __restrict__ scale,
                                      const float* __restrict__ bias,
                                      float* __restrict__ partials) {
    __shared__ __align__(16) float sd[4 * 128];
    int wid = threadIdx.x >> 6, lane = threadIdx.x & 63;
    int seg = blockIdx.x * 4 + wid;
    int s = seg_start[seg], e = s + seg_cnt[seg];
    float acc[8] = {0.f, 0.f, 0.f, 0.f, 0.f, 0.f, 0.f, 0.f};
    seg_sum_rows(src, col, s, e, lane, acc);
    cross_reduce8(acc);
    if ((lane >> 4) == 0) {
        int fl = lane & 15;
        float sc = scale[seg];
        const float4* b4 = (const float4*)(bias + fl * 8);
        float4 blo = b4[0], bhi = b4[1];
        float4* d = (float4*)(sd + wid * 128 + fl * 8);
        d[0] = make_float4(fmaxf(acc[0] * sc + blo.x, 0.f), fmaxf(acc[1] * sc + blo.y, 0.f),
                           fmaxf(acc[2] * sc + blo.z, 0.f), fmaxf(acc[3] * sc + blo.w, 0.f));
        d[1] = make_float4(fmaxf(acc[4] * sc + bhi.x, 0.f), fmaxf(acc[5] * sc + bhi.y, 0.f),
                           fmaxf(acc[6] * sc + bhi.z, 0.f), fmaxf(acc[7] * sc + bhi.w, 0.f));
    }
    __syncthreads();
    int t = threadIdx.x;
    if (t < 128) {
        partials[(size_t)blockIdx.x * 128 + t] =
            sd[t] + sd[128 + t] + sd[256 + t] + sd[384 + t];
    }
}

// ---------------- mean reduction, coalesced two-stage ----------------
__launch_bounds__(256)
__global__ void mean_stage1_kernel(const float* __restrict__ partials, float* __restrict__ partials2,
                                   int nrows) {
    __shared__ __align__(16) float4 s4[256];
    int t = threadIdx.x;
    int c4 = t & 31, r8 = t >> 5;
    float4 a = make_float4(0.f, 0.f, 0.f, 0.f);
    for (int r = blockIdx.x * 8 + r8; r < nrows; r += 256 * 8) {
        float4 v = ((const float4*)partials)[(size_t)r * 32 + c4];
        a.x += v.x; a.y += v.y; a.z += v.z; a.w += v.w;
    }
    s4[t] = a;
    __syncthreads();
    if (t < 32) {
        float4 v = s4[t];
#pragma unroll
        for (int i = 1; i < 8; ++i) {
            float4 u = s4[t + 32 * i];
            v.x += u.x; v.y += u.y; v.z += u.z; v.w += u.w;
        }
        ((float4*)partials2)[(size_t)blockIdx.x * 32 + t] = v;
    }
}

__launch_bounds__(256)
__global__ void mean_stage2_kernel(const float* __restrict__ partials2, float* __restrict__ out) {
    __shared__ __align__(16) float4 s4[256];
    int t = threadIdx.x;
    int c4 = t & 31, r8 = t >> 5;
    float4 a = make_float4(0.f, 0.f, 0.f, 0.f);
    for (int r = r8; r < 256; r += 8) {
        float4 v = ((const float4*)partials2)[(size_t)r * 32 + c4];
        a.x += v.x; a.y += v.y; a.z += v.z; a.w += v.w;
    }
    s4[t] = a;
    __syncthreads();
    if (t < 32) {
        float4 v = s4[t];
#pragma unroll
        for (int i = 1; i < 8; ++i) {
            float4 u = s4[t + 32 * i];
            v.x += u.x; v.y += u.y; v.z += u.z; v.w += u.w;
        }
        const float inv = 1.0f / (float)N_NODES;
        v.x *= inv; v.y *= inv; v.z *= inv; v.w *= inv;
        ((float4*)out)[t] = v;
    }
}

// ---------------- launch ----------------
extern "C" void kernel_launch(void* const* d_in, const int* in_sizes, int n_in,
                              void* d_out, int out_size, void* d_ws, size_t ws_size,
                              hipStream_t stream) {
    const float* x  = (const float*)d_in[0];
    const int*   ei = (const int*)d_in[1];
    const float* w1 = (const float*)d_in[2];
    const float* b1 = (const float*)d_in[3];
    const float* w2 = (const float*)d_in[4];
    const float* b2 = (const float*)d_in[5];
    float* out = (float*)d_out;
    const int* nidx = ei;
    const int* hidx = ei + N_INC;

    char* wsp = (char*)d_ws;
    size_t off = 0;
    auto alloc = [&](size_t bytes) -> void* {
        void* p = wsp + off;
        off += (bytes + 255) & ~(size_t)255;
        return p;
    };

    char* B0         = (char*)alloc((size_t)N_NODES * 128 * 2);
    char* B1         = (char*)alloc((size_t)N_NODES * 128 * 2);
    unsigned* bin_e  = (unsigned*)alloc((size_t)NBUCK * CAP * 4);
    unsigned* bin_n  = (unsigned*)alloc((size_t)NBUCK * CAP * 4);
    int* csr_e       = (int*)alloc((size_t)NBUCK * CAP * 4);
    int* csr_n       = (int*)alloc((size_t)NBUCK * CAP * 4);
    float* partials  = (float*)alloc((size_t)(N_NODES / 4) * 128 * 4);
    float* partials2 = (float*)alloc((size_t)256 * 128 * 4);
    int* segs_e      = (int*)alloc((size_t)N_NODES * 4);
    int* segc_e      = (int*)alloc((size_t)N_NODES * 4);
    int* segs_n      = (int*)alloc((size_t)N_NODES * 4);
    int* segc_n      = (int*)alloc((size_t)N_NODES * 4);
    float* scale_e   = (float*)alloc((size_t)N_NODES * 4);
    float* scale_n   = (float*)alloc((size_t)N_NODES * 4);
    short* WT1       = (short*)alloc((size_t)128 * 128 * 2);
    short* WT2       = (short*)alloc((size_t)128 * 128 * 2);
    // contiguous counter block, zeroed by wt_kernel block 0 (no memset dispatch)
    int* gcnt        = (int*)alloc((size_t)2 * NBUCK * 4);
    int* gcnt_e = gcnt;
    int* gcnt_n = gcnt + NBUCK;

    wt_kernel<<<128, 256, 0, stream>>>(w1, w2, WT1, WT2, gcnt);
    binA_kernel<<<NBLKA, 256, 0, stream>>>(nidx, hidx, gcnt_e, gcnt_n, bin_e, bin_n);
    binB2_kernel<<<2 * NBUCK, 512, 0, stream>>>(gcnt_e, bin_e, csr_e, segs_e, segc_e, scale_e,
                                                gcnt_n, bin_n, csr_n, segs_n, segc_n, scale_n);

    int gGemm = (N_NODES + 63) / 64;
    int gSeg = N_NODES / 4;

    // layer 1
    gemm_mfma_kernel<float><<<gGemm, 256, 0, stream>>>(x, WT1, (__hip_bfloat16*)B0, N_NODES);
    edge_agg_kernel<<<gSeg, 256, 0, stream>>>(B0, segs_e, segc_e, csr_e, scale_e, B1);
    node_agg_relu_kernel<<<gSeg, 256, 0, stream>>>(B1, segs_n, segc_n, csr_n, scale_n, b1, B0);
    // layer 2
    gemm_mfma_kernel<__hip_bfloat16><<<gGemm, 256, 0, stream>>>((const __hip_bfloat16*)B0, WT2,
                                                                (__hip_bfloat16*)B1, N_NODES);
    edge_agg_kernel<<<gSeg, 256, 0, stream>>>(B1, segs_e, segc_e, csr_e, scale_e, B0);
    node_agg_final_kernel<<<gSeg, 256, 0, stream>>>(B0, segs_n, segc_n, csr_n, scale_n, b2, partials);
    mean_stage1_kernel<<<256, 256, 0, stream>>>(partials, partials2, N_NODES / 4);
    mean_stage2_kernel<<<1, 256, 0, stream>>>(partials2, out);
}